// Round 1
// baseline (989.145 us; speedup 1.0000x reference)
//
#include <hip/hip_runtime.h>
#include <hip/hip_bf16.h>
#include <math.h>

#define BROWS 32768
#define NNB   8
#define DIN   256
#define DH    512
#define DOUT  256
#define MROWS 128   // rows per block
#define CH    32    // DH cols per chunk
#define NCHUNK 16
#define NCLDS 14    // h chunks kept in LDS (2 kept in regs)

typedef __attribute__((ext_vector_type(8))) short bfrag;   // 8 x bf16
typedef __attribute__((ext_vector_type(4))) float ffrag;   // MFMA accumulator
typedef __attribute__((ext_vector_type(4))) float f4v;

__device__ __forceinline__ short f2bf(float f) {
    union { float f; unsigned u; } v; v.f = f;
    unsigned r = v.u + 0x7fffu + ((v.u >> 16) & 1u);   // RNE
    return (short)(r >> 16);
}
__device__ __forceinline__ float bf2f(short s) {
    union { float f; unsigned u; } v;
    v.u = ((unsigned)(unsigned short)s) << 16;
    return v.f;
}

// Coalesced transpose + cast with gamma fold: dst[c][r] = bf16(src[r][c]*g[r])
__global__ void tcast_g(const float* __restrict__ src, const float* __restrict__ g,
                        short* __restrict__ dst, int R, int C) {
    __shared__ short t[64][67];
    const int c0 = blockIdx.x * 64, r0 = blockIdx.y * 64;
    const int lr = threadIdx.x >> 6, lc = threadIdx.x & 63;
    #pragma unroll
    for (int i = 0; i < 16; ++i) {
        int row = i * 4 + lr;
        t[row][lc] = f2bf(src[(size_t)(r0 + row) * C + c0 + lc] * g[r0 + row]);
    }
    __syncthreads();
    #pragma unroll
    for (int i = 0; i < 16; ++i) {
        int row = i * 4 + lr;
        dst[(size_t)(c0 + row) * R + r0 + lc] = t[lc][row];
    }
}

__global__ void tcast(const float* __restrict__ src, short* __restrict__ dst,
                      int R, int C) {
    __shared__ short t[64][67];
    const int c0 = blockIdx.x * 64, r0 = blockIdx.y * 64;
    const int lr = threadIdx.x >> 6, lc = threadIdx.x & 63;
    #pragma unroll
    for (int i = 0; i < 16; ++i) {
        int row = i * 4 + lr;
        t[row][lc] = f2bf(src[(size_t)(r0 + row) * C + c0 + lc]);
    }
    __syncthreads();
    #pragma unroll
    for (int i = 0; i < 16; ++i) {
        int row = i * 4 + lr;
        dst[(size_t)(c0 + row) * R + r0 + lc] = t[lc][row];
    }
}

// b1p[n] = b1[n] + sum_k beta[k] * W1[k][n]
__global__ void b1prep(const float* __restrict__ W1, const float* __restrict__ b1,
                       const float* __restrict__ beta, float* __restrict__ b1p) {
    int n = blockIdx.x * 256 + threadIdx.x;
    float acc = b1[n];
    for (int k = 0; k < DIN; ++k) acc += beta[k] * W1[(size_t)k * DH + n];
    b1p[n] = acc;
}

// w2a[h] = sum_o W2[h][o]*aw[o];  w2a[DH] = ab + sum_o b2[o]*aw[o]
__global__ void w2aprep(const float* __restrict__ W2, const float* __restrict__ aw,
                        const float* __restrict__ ab, const float* __restrict__ b2,
                        float* __restrict__ w2a) {
    int h = threadIdx.x;   // 512 threads, 1 block
    float acc = 0.f;
    for (int o = 0; o < DOUT; ++o) acc += W2[(size_t)h * DOUT + o] * aw[o];
    w2a[h] = acc;
    if (h == 0) {
        float s = ab[0];
        for (int o = 0; o < DOUT; ++o) s += b2[o] * aw[o];
        w2a[DH] = s;
    }
}

// out = (relu(h_loc) + sum_s w_s relu(h_s)) @ W2 + 2*b2
// h_s spilled per-thread to LDS (bf16); Hbar accumulated online in registers.
__global__ __launch_bounds__(512, 2)
void fused_node(const float* __restrict__ state, const float* __restrict__ nbr,
                const float* __restrict__ b1p, const float* __restrict__ b2,
                const float* __restrict__ w2a_g,
                const short* __restrict__ w1t, const short* __restrict__ w2t,
                float* __restrict__ out) {
    __shared__ short w1buf[2][CH * DIN];        // 2 x 16384 B, XOR-swizzled layout
    __shared__ short h_s[NCLDS * 512 * 8];      // 14 x 8192 B (per-thread 16B slots)
    __shared__ float b1_lds[DH];
    __shared__ float w2a_lds[DH + 1];
    __shared__ float scorep[2 * MROWS];
    __shared__ float m_lds[MROWS], l_lds[MROWS], al_lds[MROWS], pp_lds[MROWS], il_lds[MROWS];
    // total ~151.5 KB -> 1 block/CU, 8 waves

    const int tid = threadIdx.x;
    const int wv = tid >> 6, lane = tid & 63;
    const int q = lane >> 4, l16 = lane & 15;
    const int rg2 = wv >> 1, cg = wv & 1;       // stage1 grid: 4 row-groups x 2 col-halves
    const int row0 = blockIdx.x * MROWS;

    // park: linear LDS slot t, global source index inverse-swizzled
    const int t0 = tid, t1 = tid + 512;
    const int g0 = ((t0 >> 5) << 5) | ((t0 & 31) ^ ((t0 >> 5) & 7));
    const int g1 = ((t1 >> 5) << 5) | ((t1 & 31) ^ ((t1 >> 5) & 7));

    if (tid < DH) { b1_lds[tid] = b1p[tid]; w2a_lds[tid] = w2a_g[tid]; }
    if (tid == 0) w2a_lds[DH] = w2a_g[DH];
    if (tid < MROWS) { m_lds[tid] = -__builtin_huge_valf(); l_lds[tid] = 0.f; }

    // prologue: park chunk 0
    bfrag P0 = *(const bfrag*)(w1t + (size_t)g0 * 8);
    bfrag P1 = *(const bfrag*)(w1t + (size_t)g1 * 8);
    *(bfrag*)(&w1buf[0][t0 * 8]) = P0;
    *(bfrag*)(&w1buf[0][t1 * 8]) = P1;

    float hbar[NCHUNK][8];
    #pragma unroll
    for (int c = 0; c < NCHUNK; ++c)
        #pragma unroll
        for (int j = 0; j < 8; ++j) hbar[c][j] = 0.f;

    bfrag hreg14, hreg15;
    bfrag xnf[2][8];

    for (int s = 0; s <= NNB; ++s) {
        const float* xb = (s == NNB) ? (state + (size_t)row0 * DIN)
                                     : (nbr + ((size_t)s * BROWS + (size_t)row0) * DIN);
        // ---- LayerNorm (2 rows/thread-group), fully in registers ----
        #pragma unroll
        for (int rf = 0; rf < 2; ++rf) {
            const float* xr = xb + (size_t)(32 * rg2 + 16 * rf + l16) * DIN + q * 8;
            f4v xa[8], xc[8];
            #pragma unroll
            for (int kb = 0; kb < 8; ++kb) {
                xa[kb] = __builtin_nontemporal_load((const f4v*)(xr + kb * 32));
                xc[kb] = __builtin_nontemporal_load((const f4v*)(xr + kb * 32 + 4));
            }
            float sum = 0.f, ssq = 0.f;
            #pragma unroll
            for (int kb = 0; kb < 8; ++kb)
                #pragma unroll
                for (int j = 0; j < 4; ++j) {
                    sum += xa[kb][j] + xc[kb][j];
                    ssq = fmaf(xa[kb][j], xa[kb][j], fmaf(xc[kb][j], xc[kb][j], ssq));
                }
            sum += __shfl_xor(sum, 16); sum += __shfl_xor(sum, 32);
            ssq += __shfl_xor(ssq, 16); ssq += __shfl_xor(ssq, 32);
            float mean = sum * (1.f / 256.f);
            float var = ssq * (1.f / 256.f) - mean * mean;
            float rstd = rsqrtf(var + 1e-5f);
            #pragma unroll
            for (int kb = 0; kb < 8; ++kb) {
                bfrag t;
                #pragma unroll
                for (int j = 0; j < 4; ++j) {
                    t[j]     = f2bf((xa[kb][j] - mean) * rstd);
                    t[j + 4] = f2bf((xc[kb][j] - mean) * rstd);
                }
                xnf[rf][kb] = t;
            }
            __builtin_amdgcn_sched_barrier(0);   // keep the two LN windows separate (VGPR)
        }

        float sp0[4] = {0.f, 0.f, 0.f, 0.f}, sp1[4] = {0.f, 0.f, 0.f, 0.f};

        // ---- chunk loop: h = xn @ W1c + b1', relu, score-dot, spill. 1 barrier/chunk ----
        for (int c = 0; c < NCHUNK; ++c) {
            const int p = c & 1;
            __syncthreads();   // parked buf[p] visible; prev reads of buf[1-p] done
            const bool more = (c < NCHUNK - 1) || (s < NNB);
            if (more) {
                const short* sb = w1t + (size_t)((c + 1) & (NCHUNK - 1)) * (CH * DIN);
                P0 = *(const bfrag*)(sb + g0 * 8);
                P1 = *(const bfrag*)(sb + g1 * 8);
            }
            const int col = c * CH + 16 * cg + l16;
            const float bb = b1_lds[col];
            const float w2av = w2a_lds[col];
            ffrag h0 = {bb, bb, bb, bb}, h1 = {bb, bb, bb, bb};
            const short* bp = &w1buf[p][(16 * cg + l16) * DIN];
            const int e7 = l16 & 7;
            #pragma unroll
            for (int kb = 0; kb < 8; ++kb) {
                bfrag w = *(const bfrag*)(bp + (((kb * 4 + q) ^ e7) << 3));  // swizzled read
                h0 = __builtin_amdgcn_mfma_f32_16x16x32_bf16(xnf[0][kb], w, h0, 0, 0, 0);
                h1 = __builtin_amdgcn_mfma_f32_16x16x32_bf16(xnf[1][kb], w, h1, 0, 0, 0);
            }
            bfrag hb;
            #pragma unroll
            for (int r = 0; r < 4; ++r) {
                float v0 = fmaxf(h0[r], 0.f), v1 = fmaxf(h1[r], 0.f);
                sp0[r] += v0 * w2av; sp1[r] += v1 * w2av;
                hb[r] = f2bf(v0); hb[r + 4] = f2bf(v1);
            }
            if (c < NCLDS) *(bfrag*)(h_s + ((size_t)(c * 512 + tid) * 8)) = hb;
            else if (c == 14) hreg14 = hb;
            else hreg15 = hb;
            if (more) {                                  // park next chunk
                *(bfrag*)(&w1buf[1 - p][t0 * 8]) = P0;
                *(bfrag*)(&w1buf[1 - p][t1 * 8]) = P1;
            }
        }

        if (s < NNB) {
            // ---- score reduce + online softmax state ----
            #pragma unroll
            for (int r = 0; r < 4; ++r) {
                float v = sp0[r];
                v += __shfl_xor(v, 1); v += __shfl_xor(v, 2);
                v += __shfl_xor(v, 4); v += __shfl_xor(v, 8);
                sp0[r] = v;
                v = sp1[r];
                v += __shfl_xor(v, 1); v += __shfl_xor(v, 2);
                v += __shfl_xor(v, 4); v += __shfl_xor(v, 8);
                sp1[r] = v;
            }
            if (l16 == 0) {
                #pragma unroll
                for (int r = 0; r < 4; ++r) {
                    scorep[cg * MROWS + 32 * rg2 + 4 * q + r]      = sp0[r];
                    scorep[cg * MROWS + 32 * rg2 + 16 + 4 * q + r] = sp1[r];
                }
            }
            __syncthreads();
            if (tid < MROWS) {
                float sc = scorep[tid] + scorep[MROWS + tid] + w2a_lds[DH];
                float mo = m_lds[tid];
                float mn = fmaxf(mo, sc);
                float al = __expf(mo - mn);
                float pp = __expf(sc - mn);
                float ln = l_lds[tid] * al + pp;
                m_lds[tid] = mn; l_lds[tid] = ln;
                al_lds[tid] = al; pp_lds[tid] = pp;
                if (s == NNB - 1) il_lds[tid] = 1.f / ln;
            }
            __syncthreads();
            // ---- Hbar = al*Hbar + pp*relu(h)  (readback own h slots, no barrier) ----
            float al8[8], pp8[8];
            #pragma unroll
            for (int j = 0; j < 8; ++j) {
                int rr = 32 * rg2 + 16 * (j >> 2) + 4 * q + (j & 3);
                al8[j] = al_lds[rr]; pp8[j] = pp_lds[rr];
            }
            #pragma unroll
            for (int c = 0; c < NCHUNK; ++c) {
                bfrag hb = (c < NCLDS)
                             ? *(const bfrag*)(h_s + ((size_t)(c * 512 + tid) * 8))
                             : (c == 14 ? hreg14 : hreg15);
                #pragma unroll
                for (int j = 0; j < 8; ++j)
                    hbar[c][j] = al8[j] * hbar[c][j] + pp8[j] * bf2f(hb[j]);
                if ((c & 3) == 3) __builtin_amdgcn_sched_barrier(0);
            }
        }
    }

    // ---- final GEMM2: out = (h_loc + Hbar/l) @ W2 + 2*b2, once ----
    __syncthreads();
    short* a_lds = &w1buf[0][0];   // alias: weights no longer needed (128x40 shorts)
    float il8[8];
    #pragma unroll
    for (int j = 0; j < 8; ++j)
        il8[j] = il_lds[32 * rg2 + 16 * (j >> 2) + 4 * q + (j & 3)];
    const int rg = wv >> 2, cg2 = wv & 3;       // GEMM2 grid: 2 row x 4 col waves
    float b2v[4];
    #pragma unroll
    for (int ct = 0; ct < 4; ++ct) b2v[ct] = 2.f * b2[64 * cg2 + 16 * ct + l16];
    ffrag feat[4][4];
    #pragma unroll
    for (int mt = 0; mt < 4; ++mt)
        #pragma unroll
        for (int ct = 0; ct < 4; ++ct) {
            ffrag fi = {b2v[ct], b2v[ct], b2v[ct], b2v[ct]};
            feat[mt][ct] = fi;
        }
    const int akey = (q ^ (l16 >> 2)) << 3;
    #pragma unroll
    for (int c = 0; c < NCHUNK; ++c) {
        bfrag hl = (c < NCLDS)
                     ? *(const bfrag*)(h_s + ((size_t)(c * 512 + tid) * 8))
                     : (c == 14 ? hreg14 : hreg15);
        #pragma unroll
        for (int j = 0; j < 8; ++j) {
            int row = 32 * rg2 + 16 * (j >> 2) + 4 * q + (j & 3);
            int cswz = ((((16 * cg + l16) >> 3) ^ ((row >> 2) & 3)) << 3) | (l16 & 7);
            a_lds[row * 40 + cswz] = f2bf(bf2f(hl[j]) + hbar[c][j] * il8[j]);
        }
        __syncthreads();
        bfrag af[4], bfr[4];
        #pragma unroll
        for (int mt = 0; mt < 4; ++mt)
            af[mt] = *(const bfrag*)(a_lds + (64 * rg + 16 * mt + l16) * 40 + akey);
        #pragma unroll
        for (int ct = 0; ct < 4; ++ct)
            bfr[ct] = *(const bfrag*)(w2t + (size_t)(64 * cg2 + 16 * ct + l16) * DH + c * CH + q * 8);
        #pragma unroll
        for (int mt = 0; mt < 4; ++mt)
            #pragma unroll
            for (int ct = 0; ct < 4; ++ct)
                feat[mt][ct] = __builtin_amdgcn_mfma_f32_16x16x32_bf16(af[mt], bfr[ct], feat[mt][ct], 0, 0, 0);
        __syncthreads();
    }
    #pragma unroll
    for (int mt = 0; mt < 4; ++mt)
        #pragma unroll
        for (int r = 0; r < 4; ++r) {
            int row = 64 * rg + 16 * mt + 4 * q + r;
            size_t base = (size_t)(row0 + row) * DOUT + 64 * cg2 + l16;
            #pragma unroll
            for (int ct = 0; ct < 4; ++ct)
                __builtin_nontemporal_store(feat[mt][ct][r], out + base + ct * 16);
        }
}

extern "C" void kernel_launch(void* const* d_in, const int* in_sizes, int n_in,
                              void* d_out, int out_size, void* d_ws, size_t ws_size,
                              hipStream_t stream) {
    const float* state = (const float*)d_in[0];
    const float* nbr   = (const float*)d_in[1];
    const float* gamma = (const float*)d_in[2];
    const float* beta  = (const float*)d_in[3];
    const float* W1    = (const float*)d_in[4];
    const float* b1    = (const float*)d_in[5];
    const float* W2    = (const float*)d_in[6];
    const float* b2    = (const float*)d_in[7];
    const float* aw    = (const float*)d_in[8];
    const float* ab    = (const float*)d_in[9];
    float* out = (float*)d_out;

    short* w1t = (short*)d_ws;                       // [512][256] bf16, gamma-folded
    short* w2t = w1t + (size_t)DH * DIN;             // [256][512] bf16
    float* b1p = (float*)(w2t + (size_t)DOUT * DH);  // [512] fp32 (beta-folded)
    float* w2a = b1p + DH;                           // [513] fp32 (W2@aw, +attn bias fold)

    tcast_g<<<dim3(DH / 64, DIN / 64), 256, 0, stream>>>(W1, gamma, w1t, DIN, DH);
    tcast<<<dim3(DOUT / 64, DH / 64), 256, 0, stream>>>(W2, w2t, DH, DOUT);
    b1prep<<<2, 256, 0, stream>>>(W1, b1, beta, b1p);
    w2aprep<<<1, 512, 0, stream>>>(W2, aw, ab, b2, w2a);
    fused_node<<<BROWS / MROWS, 512, 0, stream>>>(state, nbr, b1p, b2, w2a,
                                                  w1t, w2t, out);
}

// Round 2
// 864.117 us; speedup vs baseline: 1.1447x; 1.1447x over previous
//
#include <hip/hip_runtime.h>
#include <hip/hip_bf16.h>
#include <math.h>

#define BROWS 32768
#define NNB   8
#define DIN   256
#define DH    512
#define DOUT  256
#define MROWS 128   // rows per block
#define CH    32    // DH cols per chunk
#define NCHUNK 16
#define NCLDS 14    // h chunks kept in LDS (2 kept in regs)

typedef __attribute__((ext_vector_type(8))) short bfrag;   // 8 x bf16
typedef __attribute__((ext_vector_type(4))) float ffrag;   // MFMA accumulator
typedef __attribute__((ext_vector_type(4))) float f4v;

__device__ __forceinline__ short f2bf(float f) {
    union { float f; unsigned u; } v; v.f = f;
    unsigned r = v.u + 0x7fffu + ((v.u >> 16) & 1u);   // RNE
    return (short)(r >> 16);
}
__device__ __forceinline__ float bf2f(short s) {
    union { float f; unsigned u; } v;
    v.u = ((unsigned)(unsigned short)s) << 16;
    return v.f;
}

// W1 prep: chunk-major, frag-transposed, gamma-folded.
// chunk c covers hidden cols n=32c..32c+31. frag f=(j,r): j=k-frag (k=8j..8j+7),
// r=n&31. dst[c*8192 + f*8 + e] = bf16(W1[8j+e][32c+r] * g[8j+e]).
// => LDS park (linear by tid) + stage1 B-frag reads are lane-contiguous (no conflicts).
__global__ void w1prep(const float* __restrict__ W1, const float* __restrict__ g,
                       short* __restrict__ dst) {
    const int c = blockIdx.x;
    const int t = threadIdx.x;
    #pragma unroll
    for (int i = 0; i < 4; ++i) {
        int f = t + 256 * i;
        int j = f >> 5, r = f & 31;
        bfrag v;
        #pragma unroll
        for (int e = 0; e < 8; ++e) {
            int k = j * 8 + e;
            v[e] = f2bf(W1[(size_t)k * DH + 32 * c + r] * g[k]);
        }
        *(bfrag*)(dst + (size_t)c * 8192 + (size_t)f * 8) = v;
    }
}

// W2 transpose+cast: dst[o][h] = bf16(W2[h][o])
__global__ void tcast(const float* __restrict__ src, short* __restrict__ dst,
                      int R, int C) {
    __shared__ short t[64][67];
    const int c0 = blockIdx.x * 64, r0 = blockIdx.y * 64;
    const int lr = threadIdx.x >> 6, lc = threadIdx.x & 63;
    #pragma unroll
    for (int i = 0; i < 16; ++i) {
        int row = i * 4 + lr;
        t[row][lc] = f2bf(src[(size_t)(r0 + row) * C + c0 + lc]);
    }
    __syncthreads();
    #pragma unroll
    for (int i = 0; i < 16; ++i) {
        int row = i * 4 + lr;
        dst[(size_t)(c0 + row) * R + r0 + lc] = t[lc][row];
    }
}

// b1p[n] = b1[n] + sum_k beta[k] * W1[k][n]
__global__ void b1prep(const float* __restrict__ W1, const float* __restrict__ b1,
                       const float* __restrict__ beta, float* __restrict__ b1p) {
    int n = blockIdx.x * 256 + threadIdx.x;
    float acc = b1[n];
    for (int k = 0; k < DIN; ++k) acc += beta[k] * W1[(size_t)k * DH + n];
    b1p[n] = acc;
}

// w2a[h] = sum_o W2[h][o]*aw[o];  w2a[DH] = ab + sum_o b2[o]*aw[o]
__global__ void w2aprep(const float* __restrict__ W2, const float* __restrict__ aw,
                        const float* __restrict__ ab, const float* __restrict__ b2,
                        float* __restrict__ w2a) {
    int h = threadIdx.x;   // 512 threads, 1 block
    float acc = 0.f;
    for (int o = 0; o < DOUT; ++o) acc += W2[(size_t)h * DOUT + o] * aw[o];
    w2a[h] = acc;
    if (h == 0) {
        float s = ab[0];
        for (int o = 0; o < DOUT; ++o) s += b2[o] * aw[o];
        w2a[DH] = s;
    }
}

// out = (relu(h_loc) + sum_s w_s relu(h_s)) @ W2 + 2*b2
__global__ __launch_bounds__(512, 2)
void fused_node(const float* __restrict__ state, const float* __restrict__ nbr,
                const float* __restrict__ b1p, const float* __restrict__ b2,
                const float* __restrict__ w2a_g,
                const short* __restrict__ w1t, const short* __restrict__ w2t,
                float* __restrict__ out) {
    __shared__ short w1buf[2][CH * DIN];        // 2 x 16384 B, frag-transposed layout
    __shared__ short h_s[NCLDS * 512 * 8];      // 14 x 8192 B (per-thread 16B slots)
    __shared__ float b1_lds[DH];
    __shared__ float w2a_lds[DH + 1];
    __shared__ float scorep[2 * MROWS];
    __shared__ float m_lds[MROWS], l_lds[MROWS], al_lds[MROWS], pp_lds[MROWS], il_lds[MROWS];
    // total ~152 KB -> 1 block/CU, 8 waves

    const int tid = threadIdx.x;
    const int wv = tid >> 6, lane = tid & 63;
    const int q = lane >> 4, l16 = lane & 15;
    const int rg2 = wv >> 1, cg = wv & 1;       // stage1 grid: 4 row-groups x 2 col-halves
    const int row0 = blockIdx.x * MROWS;

    const int t0 = tid, t1 = tid + 512;         // linear park slots (== global frag ids)

    if (tid < DH) { b1_lds[tid] = b1p[tid]; w2a_lds[tid] = w2a_g[tid]; }
    if (tid == 0) w2a_lds[DH] = w2a_g[DH];
    if (tid < MROWS) { m_lds[tid] = -__builtin_huge_valf(); l_lds[tid] = 0.f; }

    // prologue: park chunk 0 (contiguous global -> contiguous LDS)
    bfrag P0 = *(const bfrag*)(w1t + (size_t)t0 * 8);
    bfrag P1 = *(const bfrag*)(w1t + (size_t)t1 * 8);
    *(bfrag*)(&w1buf[0][t0 * 8]) = P0;
    *(bfrag*)(&w1buf[0][t1 * 8]) = P1;

    float hbar[NCHUNK][8];
    #pragma unroll
    for (int c = 0; c < NCHUNK; ++c)
        #pragma unroll
        for (int j = 0; j < 8; ++j) hbar[c][j] = 0.f;

    bfrag hreg14, hreg15;
    bfrag xnf[2][8];

    for (int s = 0; s <= NNB; ++s) {
        const float* xb = (s == NNB) ? (state + (size_t)row0 * DIN)
                                     : (nbr + ((size_t)s * BROWS + (size_t)row0) * DIN);
        // ---- LayerNorm: f32 stats, immediate bf16 keep (register diet) ----
        #pragma unroll
        for (int rf = 0; rf < 2; ++rf) {
            const float* xr = xb + (size_t)(32 * rg2 + 16 * rf + l16) * DIN + q * 8;
            float sum = 0.f, ssq = 0.f;
            bfrag xr8[8];
            #pragma unroll
            for (int hh = 0; hh < 2; ++hh) {
                f4v xa[4], xc[4];
                #pragma unroll
                for (int k2 = 0; k2 < 4; ++k2) {
                    xa[k2] = __builtin_nontemporal_load((const f4v*)(xr + (hh * 4 + k2) * 32));
                    xc[k2] = __builtin_nontemporal_load((const f4v*)(xr + (hh * 4 + k2) * 32 + 4));
                }
                #pragma unroll
                for (int k2 = 0; k2 < 4; ++k2) {
                    bfrag t;
                    #pragma unroll
                    for (int j = 0; j < 4; ++j) {
                        sum += xa[k2][j] + xc[k2][j];
                        ssq = fmaf(xa[k2][j], xa[k2][j], fmaf(xc[k2][j], xc[k2][j], ssq));
                        t[j]     = f2bf(xa[k2][j]);
                        t[j + 4] = f2bf(xc[k2][j]);
                    }
                    xr8[hh * 4 + k2] = t;
                }
                __builtin_amdgcn_sched_barrier(0);   // cap load window at 32 regs
            }
            sum += __shfl_xor(sum, 16); sum += __shfl_xor(sum, 32);
            ssq += __shfl_xor(ssq, 16); ssq += __shfl_xor(ssq, 32);
            float mean = sum * (1.f / 256.f);
            float var = ssq * (1.f / 256.f) - mean * mean;
            float rstd = rsqrtf(var + 1e-5f);
            #pragma unroll
            for (int kb = 0; kb < 8; ++kb) {
                bfrag t = xr8[kb];
                bfrag o;
                #pragma unroll
                for (int j = 0; j < 8; ++j) o[j] = f2bf((bf2f(t[j]) - mean) * rstd);
                xnf[rf][kb] = o;
            }
            __builtin_amdgcn_sched_barrier(0);       // keep rf windows separate
        }

        float sp0[4] = {0.f, 0.f, 0.f, 0.f}, sp1[4] = {0.f, 0.f, 0.f, 0.f};

        // ---- chunk loop: h = xn @ W1c + b1', relu, score-dot, spill. 1 barrier/chunk ----
        for (int c = 0; c < NCHUNK; ++c) {
            const int p = c & 1;
            __syncthreads();   // parked buf[p] visible; prev reads of buf[1-p] done
            const bool more = (c < NCHUNK - 1) || (s < NNB);
            if (more) {
                const short* sb = w1t + (size_t)((c + 1) & (NCHUNK - 1)) * (CH * DIN);
                P0 = *(const bfrag*)(sb + t0 * 8);
                P1 = *(const bfrag*)(sb + t1 * 8);
            }
            const int col = c * CH + 16 * cg + l16;
            const float bb = b1_lds[col];
            const float w2av = w2a_lds[col];
            ffrag h0 = {bb, bb, bb, bb}, h1 = {bb, bb, bb, bb};
            // frag-transposed layout: frag j=(kb*4+q) for col r=(16cg+l16) at (j*32+r)*8
            const short* bq = &w1buf[p][((16 * cg + l16) << 3) + (q << 8)];
            #pragma unroll
            for (int kb = 0; kb < 8; ++kb) {
                bfrag w = *(const bfrag*)(bq + (kb << 10));
                h0 = __builtin_amdgcn_mfma_f32_16x16x32_bf16(xnf[0][kb], w, h0, 0, 0, 0);
                h1 = __builtin_amdgcn_mfma_f32_16x16x32_bf16(xnf[1][kb], w, h1, 0, 0, 0);
            }
            bfrag hb;
            #pragma unroll
            for (int r = 0; r < 4; ++r) {
                float v0 = fmaxf(h0[r], 0.f), v1 = fmaxf(h1[r], 0.f);
                sp0[r] += v0 * w2av; sp1[r] += v1 * w2av;
                hb[r] = f2bf(v0); hb[r + 4] = f2bf(v1);
            }
            if (c < NCLDS) *(bfrag*)(h_s + ((size_t)(c * 512 + tid) * 8)) = hb;
            else if (c == 14) hreg14 = hb;
            else hreg15 = hb;
            if (more) {                                  // park next chunk
                *(bfrag*)(&w1buf[1 - p][t0 * 8]) = P0;
                *(bfrag*)(&w1buf[1 - p][t1 * 8]) = P1;
            }
        }

        if (s < NNB) {
            // ---- score reduce + online softmax state ----
            #pragma unroll
            for (int r = 0; r < 4; ++r) {
                float v = sp0[r];
                v += __shfl_xor(v, 1); v += __shfl_xor(v, 2);
                v += __shfl_xor(v, 4); v += __shfl_xor(v, 8);
                sp0[r] = v;
                v = sp1[r];
                v += __shfl_xor(v, 1); v += __shfl_xor(v, 2);
                v += __shfl_xor(v, 4); v += __shfl_xor(v, 8);
                sp1[r] = v;
            }
            if (l16 == 0) {
                #pragma unroll
                for (int r = 0; r < 4; ++r) {
                    scorep[cg * MROWS + 32 * rg2 + 4 * q + r]      = sp0[r];
                    scorep[cg * MROWS + 32 * rg2 + 16 + 4 * q + r] = sp1[r];
                }
            }
            __syncthreads();
            if (tid < MROWS) {
                float sc = scorep[tid] + scorep[MROWS + tid] + w2a_lds[DH];
                float mo = m_lds[tid];
                float mn = fmaxf(mo, sc);
                float al = __expf(mo - mn);
                float pp = __expf(sc - mn);
                float ln = l_lds[tid] * al + pp;
                m_lds[tid] = mn; l_lds[tid] = ln;
                al_lds[tid] = al; pp_lds[tid] = pp;
                if (s == NNB - 1) il_lds[tid] = 1.f / ln;
            }
            __syncthreads();
            // ---- Hbar = al*Hbar + pp*relu(h)  (own slots, no barrier needed) ----
            float al8[8], pp8[8];
            #pragma unroll
            for (int j = 0; j < 8; ++j) {
                int rr = 32 * rg2 + 16 * (j >> 2) + 4 * q + (j & 3);
                al8[j] = al_lds[rr]; pp8[j] = pp_lds[rr];
            }
            #pragma unroll
            for (int c = 0; c < NCHUNK; ++c) {
                bfrag hb = (c < NCLDS)
                             ? *(const bfrag*)(h_s + ((size_t)(c * 512 + tid) * 8))
                             : (c == 14 ? hreg14 : hreg15);
                #pragma unroll
                for (int j = 0; j < 8; ++j)
                    hbar[c][j] = al8[j] * hbar[c][j] + pp8[j] * bf2f(hb[j]);
                if ((c & 3) == 3) __builtin_amdgcn_sched_barrier(0);
            }
        }
    }

    // ---- final GEMM2: out = (h_loc + Hbar/l) @ W2 + 2*b2, once ----
    __syncthreads();
    short* a_lds = &w1buf[0][0];   // alias: weights no longer needed (128x40 shorts)
    float il8[8];
    #pragma unroll
    for (int j = 0; j < 8; ++j)
        il8[j] = il_lds[32 * rg2 + 16 * (j >> 2) + 4 * q + (j & 3)];
    const int rg = wv >> 2, cg2 = wv & 3;       // GEMM2 grid: 2 row x 4 col waves
    float b2v[4];
    #pragma unroll
    for (int ct = 0; ct < 4; ++ct) b2v[ct] = 2.f * b2[64 * cg2 + 16 * ct + l16];
    ffrag feat[4][4];
    #pragma unroll
    for (int mt = 0; mt < 4; ++mt)
        #pragma unroll
        for (int ct = 0; ct < 4; ++ct) {
            ffrag fi = {b2v[ct], b2v[ct], b2v[ct], b2v[ct]};
            feat[mt][ct] = fi;
        }
    const int akey = (q ^ (l16 >> 2)) << 3;
    #pragma unroll
    for (int c = 0; c < NCHUNK; ++c) {
        bfrag hl = (c < NCLDS)
                     ? *(const bfrag*)(h_s + ((size_t)(c * 512 + tid) * 8))
                     : (c == 14 ? hreg14 : hreg15);
        #pragma unroll
        for (int j = 0; j < 8; ++j) {
            int row = 32 * rg2 + 16 * (j >> 2) + 4 * q + (j & 3);
            int cswz = ((((16 * cg + l16) >> 3) ^ ((row >> 2) & 3)) << 3) | (l16 & 7);
            a_lds[row * 40 + cswz] = f2bf(bf2f(hl[j]) + hbar[c][j] * il8[j]);
        }
        __syncthreads();
        bfrag af[4], bfr[4];
        #pragma unroll
        for (int mt = 0; mt < 4; ++mt)
            af[mt] = *(const bfrag*)(a_lds + (64 * rg + 16 * mt + l16) * 40 + akey);
        #pragma unroll
        for (int ct = 0; ct < 4; ++ct)
            bfr[ct] = *(const bfrag*)(w2t + (size_t)(64 * cg2 + 16 * ct + l16) * DH + c * CH + q * 8);
        #pragma unroll
        for (int mt = 0; mt < 4; ++mt)
            #pragma unroll
            for (int ct = 0; ct < 4; ++ct)
                feat[mt][ct] = __builtin_amdgcn_mfma_f32_16x16x32_bf16(af[mt], bfr[ct], feat[mt][ct], 0, 0, 0);
        __syncthreads();
    }
    #pragma unroll
    for (int mt = 0; mt < 4; ++mt)
        #pragma unroll
        for (int r = 0; r < 4; ++r) {
            int row = 64 * rg + 16 * mt + 4 * q + r;
            size_t base = (size_t)(row0 + row) * DOUT + 64 * cg2 + l16;
            #pragma unroll
            for (int ct = 0; ct < 4; ++ct)
                __builtin_nontemporal_store(feat[mt][ct][r], out + base + ct * 16);
        }
}

extern "C" void kernel_launch(void* const* d_in, const int* in_sizes, int n_in,
                              void* d_out, int out_size, void* d_ws, size_t ws_size,
                              hipStream_t stream) {
    const float* state = (const float*)d_in[0];
    const float* nbr   = (const float*)d_in[1];
    const float* gamma = (const float*)d_in[2];
    const float* beta  = (const float*)d_in[3];
    const float* W1    = (const float*)d_in[4];
    const float* b1    = (const float*)d_in[5];
    const float* W2    = (const float*)d_in[6];
    const float* b2    = (const float*)d_in[7];
    const float* aw    = (const float*)d_in[8];
    const float* ab    = (const float*)d_in[9];
    float* out = (float*)d_out;

    short* w1t = (short*)d_ws;                       // [16 chunks][1024 frags][8] bf16
    short* w2t = w1t + (size_t)DH * DIN;             // [256][512] bf16
    float* b1p = (float*)(w2t + (size_t)DOUT * DH);  // [512] fp32 (beta-folded)
    float* w2a = b1p + DH;                           // [513] fp32 (W2@aw, +attn bias fold)

    w1prep<<<NCHUNK, 256, 0, stream>>>(W1, gamma, w1t);
    tcast<<<dim3(DOUT / 64, DH / 64), 256, 0, stream>>>(W2, w2t, DH, DOUT);
    b1prep<<<2, 256, 0, stream>>>(W1, b1, beta, b1p);
    w2aprep<<<1, 512, 0, stream>>>(W2, aw, ab, b2, w2a);
    fused_node<<<BROWS / MROWS, 512, 0, stream>>>(state, nbr, b1p, b2, w2a,
                                                  w1t, w2t, out);
}

// Round 3
// 848.395 us; speedup vs baseline: 1.1659x; 1.0185x over previous
//
#include <hip/hip_runtime.h>
#include <hip/hip_bf16.h>
#include <math.h>

#define BROWS 32768
#define NNB   8
#define DIN   256
#define DH    512
#define DOUT  256
#define MROWS 128   // rows per block
#define CH    32    // DH cols per chunk
#define NCHUNK 16
#define NCLDS 14    // h chunks kept in LDS (2 kept in regs)

typedef __attribute__((ext_vector_type(8))) short bfrag;   // 8 x bf16
typedef __attribute__((ext_vector_type(4))) float ffrag;   // MFMA accumulator
typedef __attribute__((ext_vector_type(4))) float f4v;

__device__ __forceinline__ short f2bf(float f) {
    union { float f; unsigned u; } v; v.f = f;
    unsigned r = v.u + 0x7fffu + ((v.u >> 16) & 1u);   // RNE
    return (short)(r >> 16);
}
__device__ __forceinline__ float bf2f(short s) {
    union { float f; unsigned u; } v;
    v.u = ((unsigned)(unsigned short)s) << 16;
    return v.f;
}

// W1 prep: chunk-major, frag-transposed, gamma-folded.
// chunk c covers hidden cols n=32c..32c+31. frag f=(j,r): j=k-frag (k=8j..8j+7),
// r=n&31. dst[c*8192 + f*8 + e] = bf16(W1[8j+e][32c+r] * g[8j+e]).
// => LDS park (linear by tid) + stage1 B-frag reads are lane-contiguous (no conflicts).
__global__ void w1prep(const float* __restrict__ W1, const float* __restrict__ g,
                       short* __restrict__ dst) {
    const int c = blockIdx.x;
    const int t = threadIdx.x;
    #pragma unroll
    for (int i = 0; i < 4; ++i) {
        int f = t + 256 * i;
        int j = f >> 5, r = f & 31;
        bfrag v;
        #pragma unroll
        for (int e = 0; e < 8; ++e) {
            int k = j * 8 + e;
            v[e] = f2bf(W1[(size_t)k * DH + 32 * c + r] * g[k]);
        }
        *(bfrag*)(dst + (size_t)c * 8192 + (size_t)f * 8) = v;
    }
}

// W2 transpose+cast: dst[o][h] = bf16(W2[h][o])
__global__ void tcast(const float* __restrict__ src, short* __restrict__ dst,
                      int R, int C) {
    __shared__ short t[64][67];
    const int c0 = blockIdx.x * 64, r0 = blockIdx.y * 64;
    const int lr = threadIdx.x >> 6, lc = threadIdx.x & 63;
    #pragma unroll
    for (int i = 0; i < 16; ++i) {
        int row = i * 4 + lr;
        t[row][lc] = f2bf(src[(size_t)(r0 + row) * C + c0 + lc]);
    }
    __syncthreads();
    #pragma unroll
    for (int i = 0; i < 16; ++i) {
        int row = i * 4 + lr;
        dst[(size_t)(c0 + row) * R + r0 + lc] = t[lc][row];
    }
}

// b1p[n] = b1[n] + sum_k beta[k] * W1[k][n]
__global__ void b1prep(const float* __restrict__ W1, const float* __restrict__ b1,
                       const float* __restrict__ beta, float* __restrict__ b1p) {
    int n = blockIdx.x * 256 + threadIdx.x;
    float acc = b1[n];
    for (int k = 0; k < DIN; ++k) acc += beta[k] * W1[(size_t)k * DH + n];
    b1p[n] = acc;
}

// w2a[h] = sum_o W2[h][o]*aw[o];  w2a[DH] = ab + sum_o b2[o]*aw[o]
// wave-per-8h, coalesced, shuffle reduce. grid 16 x 256.
__global__ void w2aprep(const float* __restrict__ W2, const float* __restrict__ aw,
                        const float* __restrict__ ab, const float* __restrict__ b2,
                        float* __restrict__ w2a) {
    const int wave = (blockIdx.x * blockDim.x + threadIdx.x) >> 6;  // 0..63
    const int lane = threadIdx.x & 63;
    #pragma unroll
    for (int i = 0; i < 8; ++i) {
        int h = wave * 8 + i;
        float acc = 0.f;
        #pragma unroll
        for (int e = 0; e < 4; ++e)
            acc += W2[(size_t)h * DOUT + lane + 64 * e] * aw[lane + 64 * e];
        acc += __shfl_xor(acc, 1);  acc += __shfl_xor(acc, 2);
        acc += __shfl_xor(acc, 4);  acc += __shfl_xor(acc, 8);
        acc += __shfl_xor(acc, 16); acc += __shfl_xor(acc, 32);
        if (lane == 0) w2a[h] = acc;
    }
    if (wave == 0) {
        float s = 0.f;
        #pragma unroll
        for (int e = 0; e < 4; ++e) s += b2[lane + 64 * e] * aw[lane + 64 * e];
        s += __shfl_xor(s, 1);  s += __shfl_xor(s, 2);
        s += __shfl_xor(s, 4);  s += __shfl_xor(s, 8);
        s += __shfl_xor(s, 16); s += __shfl_xor(s, 32);
        if (lane == 0) w2a[DH] = ab[0] + s;
    }
}

// out = (relu(h_loc) + sum_s w_s relu(h_s)) @ W2 + 2*b2
// LDS caps us at 1 workgroup/CU (= 2 waves/SIMD), so pin waves_per_eu(2,2):
// VGPR budget 256/wave, which hbar[16][8]+xnf needs. (launch_bounds(512,2)
// was read as 4 waves/EU -> 128 VGPR cap -> 537 MB/dir scratch spill.)
__global__ __launch_bounds__(512) __attribute__((amdgpu_waves_per_eu(2, 2)))
void fused_node(const float* __restrict__ state, const float* __restrict__ nbr,
                const float* __restrict__ b1p, const float* __restrict__ b2,
                const float* __restrict__ w2a_g,
                const short* __restrict__ w1t, const short* __restrict__ w2t,
                float* __restrict__ out) {
    __shared__ short w1buf[2][CH * DIN];        // 2 x 16384 B, frag-transposed layout
    __shared__ short h_s[NCLDS * 512 * 8];      // 14 x 8192 B (per-thread 16B slots)
    __shared__ float b1_lds[DH];
    __shared__ float w2a_lds[DH + 1];
    __shared__ float scorep[2 * MROWS];
    __shared__ float m_lds[MROWS], l_lds[MROWS], al_lds[MROWS], pp_lds[MROWS], il_lds[MROWS];
    // total ~152 KB -> 1 block/CU, 8 waves

    const int tid = threadIdx.x;
    const int wv = tid >> 6, lane = tid & 63;
    const int q = lane >> 4, l16 = lane & 15;
    const int rg2 = wv >> 1, cg = wv & 1;       // stage1 grid: 4 row-groups x 2 col-halves
    const int row0 = blockIdx.x * MROWS;

    const int t0 = tid, t1 = tid + 512;         // linear park slots (== global frag ids)

    if (tid < DH) { b1_lds[tid] = b1p[tid]; w2a_lds[tid] = w2a_g[tid]; }
    if (tid == 0) w2a_lds[DH] = w2a_g[DH];
    if (tid < MROWS) { m_lds[tid] = -__builtin_huge_valf(); l_lds[tid] = 0.f; }

    // prologue: park chunk 0 (contiguous global -> contiguous LDS)
    bfrag P0 = *(const bfrag*)(w1t + (size_t)t0 * 8);
    bfrag P1 = *(const bfrag*)(w1t + (size_t)t1 * 8);
    *(bfrag*)(&w1buf[0][t0 * 8]) = P0;
    *(bfrag*)(&w1buf[0][t1 * 8]) = P1;

    float hbar[NCHUNK][8];
    #pragma unroll
    for (int c = 0; c < NCHUNK; ++c)
        #pragma unroll
        for (int j = 0; j < 8; ++j) hbar[c][j] = 0.f;

    bfrag hreg14, hreg15;
    bfrag xnf[2][8];

    for (int s = 0; s <= NNB; ++s) {
        const float* xb = (s == NNB) ? (state + (size_t)row0 * DIN)
                                     : (nbr + ((size_t)s * BROWS + (size_t)row0) * DIN);
        // ---- LayerNorm: f32 stats, immediate bf16 keep (register diet) ----
        #pragma unroll
        for (int rf = 0; rf < 2; ++rf) {
            const float* xr = xb + (size_t)(32 * rg2 + 16 * rf + l16) * DIN + q * 8;
            float sum = 0.f, ssq = 0.f;
            bfrag xr8[8];
            #pragma unroll
            for (int hh = 0; hh < 2; ++hh) {
                f4v xa[4], xc[4];
                #pragma unroll
                for (int k2 = 0; k2 < 4; ++k2) {
                    xa[k2] = __builtin_nontemporal_load((const f4v*)(xr + (hh * 4 + k2) * 32));
                    xc[k2] = __builtin_nontemporal_load((const f4v*)(xr + (hh * 4 + k2) * 32 + 4));
                }
                #pragma unroll
                for (int k2 = 0; k2 < 4; ++k2) {
                    bfrag t;
                    #pragma unroll
                    for (int j = 0; j < 4; ++j) {
                        sum += xa[k2][j] + xc[k2][j];
                        ssq = fmaf(xa[k2][j], xa[k2][j], fmaf(xc[k2][j], xc[k2][j], ssq));
                        t[j]     = f2bf(xa[k2][j]);
                        t[j + 4] = f2bf(xc[k2][j]);
                    }
                    xr8[hh * 4 + k2] = t;
                }
                __builtin_amdgcn_sched_barrier(0);   // cap load window at 32 regs
            }
            sum += __shfl_xor(sum, 16); sum += __shfl_xor(sum, 32);
            ssq += __shfl_xor(ssq, 16); ssq += __shfl_xor(ssq, 32);
            float mean = sum * (1.f / 256.f);
            float var = ssq * (1.f / 256.f) - mean * mean;
            float rstd = rsqrtf(var + 1e-5f);
            #pragma unroll
            for (int kb = 0; kb < 8; ++kb) {
                bfrag t = xr8[kb];
                bfrag o;
                #pragma unroll
                for (int j = 0; j < 8; ++j) o[j] = f2bf((bf2f(t[j]) - mean) * rstd);
                xnf[rf][kb] = o;
            }
            __builtin_amdgcn_sched_barrier(0);       // keep rf windows separate
        }

        float sp0[4] = {0.f, 0.f, 0.f, 0.f}, sp1[4] = {0.f, 0.f, 0.f, 0.f};

        // ---- chunk loop: h = xn @ W1c + b1', relu, score-dot, spill. 1 barrier/chunk ----
        for (int c = 0; c < NCHUNK; ++c) {
            const int p = c & 1;
            __syncthreads();   // parked buf[p] visible; prev reads of buf[1-p] done
            const bool more = (c < NCHUNK - 1) || (s < NNB);
            if (more) {
                const short* sb = w1t + (size_t)((c + 1) & (NCHUNK - 1)) * (CH * DIN);
                P0 = *(const bfrag*)(sb + t0 * 8);
                P1 = *(const bfrag*)(sb + t1 * 8);
            }
            const int col = c * CH + 16 * cg + l16;
            const float bb = b1_lds[col];
            const float w2av = w2a_lds[col];
            ffrag h0 = {bb, bb, bb, bb}, h1 = {bb, bb, bb, bb};
            // frag-transposed layout: frag j=(kb*4+q) for col r=(16cg+l16) at (j*32+r)*8
            const short* bq = &w1buf[p][((16 * cg + l16) << 3) + (q << 8)];
            #pragma unroll
            for (int kb = 0; kb < 8; ++kb) {
                bfrag w = *(const bfrag*)(bq + (kb << 10));
                h0 = __builtin_amdgcn_mfma_f32_16x16x32_bf16(xnf[0][kb], w, h0, 0, 0, 0);
                h1 = __builtin_amdgcn_mfma_f32_16x16x32_bf16(xnf[1][kb], w, h1, 0, 0, 0);
            }
            bfrag hb;
            #pragma unroll
            for (int r = 0; r < 4; ++r) {
                float v0 = fmaxf(h0[r], 0.f), v1 = fmaxf(h1[r], 0.f);
                sp0[r] += v0 * w2av; sp1[r] += v1 * w2av;
                hb[r] = f2bf(v0); hb[r + 4] = f2bf(v1);
            }
            if (c < NCLDS) *(bfrag*)(h_s + ((size_t)(c * 512 + tid) * 8)) = hb;
            else if (c == 14) hreg14 = hb;
            else hreg15 = hb;
            if (more) {                                  // park next chunk
                *(bfrag*)(&w1buf[1 - p][t0 * 8]) = P0;
                *(bfrag*)(&w1buf[1 - p][t1 * 8]) = P1;
            }
        }

        if (s < NNB) {
            // ---- score reduce + online softmax state ----
            #pragma unroll
            for (int r = 0; r < 4; ++r) {
                float v = sp0[r];
                v += __shfl_xor(v, 1); v += __shfl_xor(v, 2);
                v += __shfl_xor(v, 4); v += __shfl_xor(v, 8);
                sp0[r] = v;
                v = sp1[r];
                v += __shfl_xor(v, 1); v += __shfl_xor(v, 2);
                v += __shfl_xor(v, 4); v += __shfl_xor(v, 8);
                sp1[r] = v;
            }
            if (l16 == 0) {
                #pragma unroll
                for (int r = 0; r < 4; ++r) {
                    scorep[cg * MROWS + 32 * rg2 + 4 * q + r]      = sp0[r];
                    scorep[cg * MROWS + 32 * rg2 + 16 + 4 * q + r] = sp1[r];
                }
            }
            __syncthreads();
            if (tid < MROWS) {
                float sc = scorep[tid] + scorep[MROWS + tid] + w2a_lds[DH];
                float mo = m_lds[tid];
                float mn = fmaxf(mo, sc);
                float al = __expf(mo - mn);
                float pp = __expf(sc - mn);
                float ln = l_lds[tid] * al + pp;
                m_lds[tid] = mn; l_lds[tid] = ln;
                al_lds[tid] = al; pp_lds[tid] = pp;
                if (s == NNB - 1) il_lds[tid] = 1.f / ln;
            }
            __syncthreads();
            // ---- Hbar = al*Hbar + pp*relu(h)  (own slots, no barrier needed) ----
            float al8[8], pp8[8];
            #pragma unroll
            for (int j = 0; j < 8; ++j) {
                int rr = 32 * rg2 + 16 * (j >> 2) + 4 * q + (j & 3);
                al8[j] = al_lds[rr]; pp8[j] = pp_lds[rr];
            }
            #pragma unroll
            for (int c = 0; c < NCHUNK; ++c) {
                bfrag hb = (c < NCLDS)
                             ? *(const bfrag*)(h_s + ((size_t)(c * 512 + tid) * 8))
                             : (c == 14 ? hreg14 : hreg15);
                #pragma unroll
                for (int j = 0; j < 8; ++j)
                    hbar[c][j] = al8[j] * hbar[c][j] + pp8[j] * bf2f(hb[j]);
                if ((c & 3) == 3) __builtin_amdgcn_sched_barrier(0);
            }
        }
    }

    // ---- final GEMM2: out = (h_loc + Hbar/l) @ W2 + 2*b2, once ----
    __syncthreads();
    short* a_lds = &w1buf[0][0];   // alias: weights no longer needed (128x40 shorts)
    float il8[8];
    #pragma unroll
    for (int j = 0; j < 8; ++j)
        il8[j] = il_lds[32 * rg2 + 16 * (j >> 2) + 4 * q + (j & 3)];
    const int rg = wv >> 2, cg2 = wv & 3;       // GEMM2 grid: 2 row x 4 col waves
    float b2v[4];
    #pragma unroll
    for (int ct = 0; ct < 4; ++ct) b2v[ct] = 2.f * b2[64 * cg2 + 16 * ct + l16];
    ffrag feat[4][4];
    #pragma unroll
    for (int mt = 0; mt < 4; ++mt)
        #pragma unroll
        for (int ct = 0; ct < 4; ++ct) {
            ffrag fi = {b2v[ct], b2v[ct], b2v[ct], b2v[ct]};
            feat[mt][ct] = fi;
        }
    const int akey = (q ^ (l16 >> 2)) << 3;
    #pragma unroll
    for (int c = 0; c < NCHUNK; ++c) {
        bfrag hl = (c < NCLDS)
                     ? *(const bfrag*)(h_s + ((size_t)(c * 512 + tid) * 8))
                     : (c == 14 ? hreg14 : hreg15);
        #pragma unroll
        for (int j = 0; j < 8; ++j) {
            int row = 32 * rg2 + 16 * (j >> 2) + 4 * q + (j & 3);
            int cswz = ((((16 * cg + l16) >> 3) ^ ((row >> 2) & 3)) << 3) | (l16 & 7);
            a_lds[row * 40 + cswz] = f2bf(bf2f(hl[j]) + hbar[c][j] * il8[j]);
        }
        __syncthreads();
        bfrag af[4], bfr[4];
        #pragma unroll
        for (int mt = 0; mt < 4; ++mt)
            af[mt] = *(const bfrag*)(a_lds + (64 * rg + 16 * mt + l16) * 40 + akey);
        #pragma unroll
        for (int ct = 0; ct < 4; ++ct)
            bfr[ct] = *(const bfrag*)(w2t + (size_t)(64 * cg2 + 16 * ct + l16) * DH + c * CH + q * 8);
        #pragma unroll
        for (int mt = 0; mt < 4; ++mt)
            #pragma unroll
            for (int ct = 0; ct < 4; ++ct)
                feat[mt][ct] = __builtin_amdgcn_mfma_f32_16x16x32_bf16(af[mt], bfr[ct], feat[mt][ct], 0, 0, 0);
        __syncthreads();
    }
    #pragma unroll
    for (int mt = 0; mt < 4; ++mt)
        #pragma unroll
        for (int r = 0; r < 4; ++r) {
            int row = 64 * rg + 16 * mt + 4 * q + r;
            size_t base = (size_t)(row0 + row) * DOUT + 64 * cg2 + l16;
            #pragma unroll
            for (int ct = 0; ct < 4; ++ct)
                __builtin_nontemporal_store(feat[mt][ct][r], out + base + ct * 16);
        }
}

extern "C" void kernel_launch(void* const* d_in, const int* in_sizes, int n_in,
                              void* d_out, int out_size, void* d_ws, size_t ws_size,
                              hipStream_t stream) {
    const float* state = (const float*)d_in[0];
    const float* nbr   = (const float*)d_in[1];
    const float* gamma = (const float*)d_in[2];
    const float* beta  = (const float*)d_in[3];
    const float* W1    = (const float*)d_in[4];
    const float* b1    = (const float*)d_in[5];
    const float* W2    = (const float*)d_in[6];
    const float* b2    = (const float*)d_in[7];
    const float* aw    = (const float*)d_in[8];
    const float* ab    = (const float*)d_in[9];
    float* out = (float*)d_out;

    short* w1t = (short*)d_ws;                       // [16 chunks][1024 frags][8] bf16
    short* w2t = w1t + (size_t)DH * DIN;             // [256][512] bf16
    float* b1p = (float*)(w2t + (size_t)DOUT * DH);  // [512] fp32 (beta-folded)
    float* w2a = b1p + DH;                           // [513] fp32 (W2@aw, +attn bias fold)

    w1prep<<<NCHUNK, 256, 0, stream>>>(W1, gamma, w1t);
    tcast<<<dim3(DOUT / 64, DH / 64), 256, 0, stream>>>(W2, w2t, DH, DOUT);
    b1prep<<<2, 256, 0, stream>>>(W1, b1, beta, b1p);
    w2aprep<<<16, 256, 0, stream>>>(W2, aw, ab, b2, w2a);
    fused_node<<<BROWS / MROWS, 512, 0, stream>>>(state, nbr, b1p, b2, w2a,
                                                  w1t, w2t, out);
}